// Round 3
// baseline (1061.041 us; speedup 1.0000x reference)
//
#include <hip/hip_runtime.h>
#include <hip/hip_bf16.h>

#define S_DIM 1024
#define R_DIM 512
#define C_DIM 256
#define BS 64
#define SB (S_DIM / BS)   // 16

#define XN_OFF (16u << 20)                       // xn cache at ws+16MB
#define XN_BYTES (512ull * 1024ull * 256ull * 2ull)  // 268435456

typedef __attribute__((ext_vector_type(8))) short short8;
typedef __attribute__((ext_vector_type(8))) unsigned short ushort8v;
typedef __attribute__((ext_vector_type(4))) unsigned short ushort4v;
typedef __attribute__((ext_vector_type(4))) float floatx4;

__device__ inline float bf2f(unsigned short u) {
    return __uint_as_float(((unsigned int)u) << 16);
}
__device__ inline unsigned short f2bf(float f) {
    unsigned int x = __float_as_uint(f);
    unsigned int r = ((x >> 16) & 1u) + 0x7fffu;
    return (unsigned short)((x + r) >> 16);
}

__device__ inline void async16(unsigned short* lds, const unsigned short* g) {
    __builtin_amdgcn_global_load_lds(
        (const __attribute__((address_space(1))) void*)g,
        (__attribute__((address_space(3))) void*)lds, 16, 0, 0);
}

// ---------------- prep: build transposed bf16 weight copies ----------------
__global__ __launch_bounds__(256) void prep_kernel(
        const float* __restrict__ Wk, const float* __restrict__ Wv,
        const float* __restrict__ Wg, const float* __restrict__ Wf,
        unsigned short* __restrict__ wgT, unsigned short* __restrict__ wfhi,
        unsigned short* __restrict__ wflo, unsigned short* __restrict__ wkvT) {
    int b = blockIdx.x;    // output column index (0..255)
    int k = threadIdx.x;   // k index (0..255)
    wgT[b * 256 + k] = f2bf(Wg[k * 256 + b]);
    float w = Wf[k * 256 + b];
    unsigned short hi = f2bf(w);
    wfhi[b * 256 + k] = hi;
    wflo[b * 256 + k] = f2bf(w - bf2f(hi));
    if (b < 64) {
        float t = (b < 32) ? Wk[k * 32 + b] : Wv[k * 32 + (b - 32)];
        wkvT[b * 256 + k] = f2bf(t);
    }
}

// ------------- stage 64 LayerNorm'd rows (bf16) into LDS [64][264] ---------
template <int CACHE>
__device__ inline void stage_xn(const float* __restrict__ x,
                                const float* __restrict__ lns,
                                const float* __restrict__ lnb,
                                int s0, int r, unsigned short* xn,
                                unsigned short* __restrict__ xnws) {
    const int t = threadIdx.x;
    const int row = t >> 2;        // 0..63
    const int q = t & 3;           // quarter of the row
    const size_t base = ((size_t)(s0 + row) * R_DIM + r) * C_DIM + q * 64;
    const float4* gp = reinterpret_cast<const float4*>(x + base);
    float4 v[16];
    float sum = 0.f, sq = 0.f;
#pragma unroll
    for (int i = 0; i < 16; i++) {
        v[i] = gp[i];
        sum += v[i].x + v[i].y + v[i].z + v[i].w;
        sq  += v[i].x * v[i].x + v[i].y * v[i].y + v[i].z * v[i].z + v[i].w * v[i].w;
    }
    sum += __shfl_xor(sum, 1); sq += __shfl_xor(sq, 1);
    sum += __shfl_xor(sum, 2); sq += __shfl_xor(sq, 2);
    float mu = sum * (1.f / 256.f);
    float var = sq * (1.f / 256.f) - mu * mu;
    float rs = rsqrtf(var + 1e-5f);
    const float4* sp = reinterpret_cast<const float4*>(lns + q * 64);
    const float4* bp = reinterpret_cast<const float4*>(lnb + q * 64);
    unsigned short* wp = xn + row * 264 + q * 64;
    unsigned short* gw = CACHE ? (xnws + ((size_t)(s0 + row) * R_DIM + r) * C_DIM + q * 64)
                               : nullptr;
#pragma unroll
    for (int i = 0; i < 16; i += 2) {
        float4 g0 = sp[i],     b0 = bp[i];
        float4 g1 = sp[i + 1], b1 = bp[i + 1];
        ushort8v u;
        u[0] = f2bf((v[i].x     - mu) * rs * g0.x + b0.x);
        u[1] = f2bf((v[i].y     - mu) * rs * g0.y + b0.y);
        u[2] = f2bf((v[i].z     - mu) * rs * g0.z + b0.z);
        u[3] = f2bf((v[i].w     - mu) * rs * g0.w + b0.w);
        u[4] = f2bf((v[i + 1].x - mu) * rs * g1.x + b1.x);
        u[5] = f2bf((v[i + 1].y - mu) * rs * g1.y + b1.y);
        u[6] = f2bf((v[i + 1].z - mu) * rs * g1.z + b1.z);
        u[7] = f2bf((v[i + 1].w - mu) * rs * g1.w + b1.w);
        *reinterpret_cast<ushort8v*>(wp + i * 4) = u;
        if (CACHE) *reinterpret_cast<ushort8v*>(gw + i * 4) = u;
    }
}

// ---------------- K1: k/v + masked column sums -----------------------------
template <int CACHE>
__global__ __launch_bounds__(256, 4) void k1_kernel(
        const float* __restrict__ x, const float* __restrict__ mask,
        const float* __restrict__ lns, const float* __restrict__ lnb,
        const unsigned short* __restrict__ wkvT, unsigned short* __restrict__ kv,
        float* __restrict__ qsum, float* __restrict__ msum,
        unsigned short* __restrict__ xnws) {
    __shared__ unsigned short xn[64 * 264];
    __shared__ float mk[64];
    const int sblk = blockIdx.x, r = blockIdx.y;
    const int s0 = sblk * BS;
    const int t = threadIdx.x;
    stage_xn<CACHE>(x, lns, lnb, s0, r, xn, xnws);
    if (t < 64) mk[t] = mask[(size_t)(s0 + t) * R_DIM + r];
    __syncthreads();

    // swapped MFMA: D[col, row] -> thread holds 4 contiguous cols per n
    const int w = t >> 6, l = t & 63;
    const int lr = l & 15, lk4 = l >> 4;
    floatx4 acc[4] = {};
    const unsigned short* arow = xn + (w * 16 + lr) * 264 + lk4 * 8;
#pragma unroll
    for (int kk = 0; kk < 256; kk += 32) {
        short8 a = *reinterpret_cast<const short8*>(arow + kk);
#pragma unroll
        for (int n = 0; n < 4; n++) {
            short8 b = *reinterpret_cast<const short8*>(wkvT + (n * 16 + lr) * 256 + kk + lk4 * 8);
            acc[n] = __builtin_amdgcn_mfma_f32_16x16x32_bf16(b, a, acc[n], 0, 0, 0);
        }
    }
    unsigned short* kvp = kv + ((size_t)r * S_DIM + s0 + w * 16 + lr) * 64 + lk4 * 4;
#pragma unroll
    for (int n = 0; n < 4; n++) {
        ushort4v pk;
        pk[0] = f2bf(acc[n][0]);
        pk[1] = f2bf(acc[n][1]);
        pk[2] = f2bf(acc[n][2]);
        pk[3] = f2bf(acc[n][3]);
        *reinterpret_cast<ushort4v*>(kvp + n * 16) = pk;
    }
    // masked column sums over the 64 rows
    float cs = 0.f;
    const int c = t;
#pragma unroll 8
    for (int row = 0; row < 64; row++) cs += bf2f(xn[row * 264 + c]) * mk[row];
    qsum[((size_t)r * SB + sblk) * 256 + c] = cs;
    if (t < 64) {
        float m = mk[t];
#pragma unroll
        for (int off = 32; off; off >>= 1) m += __shfl_xor(m, off);
        if (t == 0) msum[r * SB + sblk] = m;
    }
}

// ---------------- K2: q_avg, q, softmax, o ---------------------------------
__global__ __launch_bounds__(256) void k2_kernel(
        const float* __restrict__ mask, const float* __restrict__ Wq,
        const float* __restrict__ qsum, const float* __restrict__ msum,
        const unsigned short* __restrict__ kv, float* __restrict__ oout) {
    __shared__ float qavg[256];
    __shared__ float qh[256];
    __shared__ float lg[8][1024];
    __shared__ float red[8];
    __shared__ unsigned short vtT[32 * 264];   // v^T tile: [ch][s-chunk rotated]
    const int r = blockIdx.x;
    const int t = threadIdx.x;

    float ms = 0.f;
#pragma unroll
    for (int i = 0; i < SB; i++) ms += msum[r * SB + i];
    float inv = 1.f / (ms + 1e-10f);
    float qs = 0.f;
#pragma unroll
    for (int i = 0; i < SB; i++) qs += qsum[((size_t)r * SB + i) * 256 + t];
    qavg[t] = qs * inv;
    __syncthreads();

    float accq = 0.f;
    for (int c = 0; c < 256; c++) accq += qavg[c] * Wq[c * 256 + t];
    qh[t] = accq * 0.17677669529663687f;   // CH^-0.5
    __syncthreads();

    const unsigned short* kvr = kv + (size_t)r * S_DIM * 64;
#pragma unroll
    for (int i = 0; i < 4; i++) {
        int s = i * 256 + t;
        float bias = 1e9f * (mask[(size_t)s * R_DIM + r] - 1.f);
        const unsigned int* kp = reinterpret_cast<const unsigned int*>(kvr + (size_t)s * 64);
        float kvals[32];
#pragma unroll
        for (int j = 0; j < 16; j++) {
            unsigned int u = kp[j];
            kvals[2 * j]     = __uint_as_float(u << 16);
            kvals[2 * j + 1] = __uint_as_float(u & 0xffff0000u);
        }
#pragma unroll
        for (int h = 0; h < 8; h++) {
            float d = 0.f;
#pragma unroll
            for (int ch = 0; ch < 32; ch++) d += qh[h * 32 + ch] * kvals[ch];
            lg[h][s] = d + bias;
        }
    }
    __syncthreads();

    for (int h = 0; h < 8; h++) {
        float mx = -1e30f;
#pragma unroll
        for (int i = 0; i < 4; i++) mx = fmaxf(mx, lg[h][i * 256 + t]);
        for (int off = 32; off; off >>= 1) mx = fmaxf(mx, __shfl_xor(mx, off));
        if ((t & 63) == 0) red[t >> 6] = mx;
        __syncthreads();
        mx = fmaxf(fmaxf(red[0], red[1]), fmaxf(red[2], red[3]));
        float sm = 0.f;
#pragma unroll
        for (int i = 0; i < 4; i++) {
            float e = __expf(lg[h][i * 256 + t] - mx);
            lg[h][i * 256 + t] = e;
            sm += e;
        }
        for (int off = 32; off; off >>= 1) sm += __shfl_xor(sm, off);
        if ((t & 63) == 0) red[4 + (t >> 6)] = sm;
        __syncthreads();
        sm = red[4] + red[5] + red[6] + red[7];
        float isv = 1.f / sm;
#pragma unroll
        for (int i = 0; i < 4; i++) lg[h][i * 256 + t] *= isv;
        __syncthreads();
    }

    // o = w @ v via transposed v tiles (vectorized LDS reads)
    const int h = t >> 5, ch = t & 31;
    const int p = t >> 3, q = t & 7;
    float o = 0.f;
    for (int st = 0; st < 4; st++) {
        __syncthreads();   // prior-tile reads done
        {
            const unsigned short* src = kvr + ((size_t)(st * 256 + t)) * 64 + 32;
            ushort8v v0 = reinterpret_cast<const ushort8v*>(src)[0];
            ushort8v v1 = reinterpret_cast<const ushort8v*>(src)[1];
            ushort8v v2 = reinterpret_cast<const ushort8v*>(src)[2];
            ushort8v v3 = reinterpret_cast<const ushort8v*>(src)[3];
            // channel c holds s-chunk p at rotated slot (p+c)&31
#pragma unroll
            for (int j = 0; j < 8; j++)
                vtT[(j)      * 264 + (((p + j)      & 31) * 8 + q)] = v0[j];
#pragma unroll
            for (int j = 0; j < 8; j++)
                vtT[(j + 8)  * 264 + (((p + j + 8)  & 31) * 8 + q)] = v1[j];
#pragma unroll
            for (int j = 0; j < 8; j++)
                vtT[(j + 16) * 264 + (((p + j + 16) & 31) * 8 + q)] = v2[j];
#pragma unroll
            for (int j = 0; j < 8; j++)
                vtT[(j + 24) * 264 + (((p + j + 24) & 31) * 8 + q)] = v3[j];
        }
        __syncthreads();
        const unsigned short* vrow = vtT + ch * 264;
        const float* lrow = &lg[h][st * 256];
#pragma unroll 8
        for (int g8 = 0; g8 < 32; g8++) {
            ushort8v v8 = *reinterpret_cast<const ushort8v*>(vrow + ((g8 + ch) & 31) * 8);
            float4 l0 = *reinterpret_cast<const float4*>(lrow + g8 * 8);
            float4 l1 = *reinterpret_cast<const float4*>(lrow + g8 * 8 + 4);
            o += l0.x * bf2f(v8[0]) + l0.y * bf2f(v8[1]) + l0.z * bf2f(v8[2]) + l0.w * bf2f(v8[3])
               + l1.x * bf2f(v8[4]) + l1.y * bf2f(v8[5]) + l1.z * bf2f(v8[6]) + l1.w * bf2f(v8[7]);
        }
    }
    oout[r * 256 + t] = o;
}

// ---------------- K3 (recompute path, unchanged fallback) ------------------
__global__ __launch_bounds__(256, 4) void k3r_kernel(
        const float* __restrict__ x, const float* __restrict__ lns,
        const float* __restrict__ lnb, const unsigned short* __restrict__ wgT,
        const unsigned short* __restrict__ wfhi, const unsigned short* __restrict__ wflo,
        const float* __restrict__ oin, const float* __restrict__ bg,
        const float* __restrict__ bfv, float* __restrict__ out) {
    __shared__ unsigned short xa[64 * 264];
    const int sblk = blockIdx.x, r = blockIdx.y;
    const int s0 = sblk * BS;
    const int t = threadIdx.x;
    stage_xn<0>(x, lns, lnb, s0, r, xa, nullptr);
    __syncthreads();

    const int w = t >> 6, l = t & 63;
    const int lr = l & 15, lk4 = (l >> 4);
    const int colbase = w * 64;

    float bgv[4], ov[4];
#pragma unroll
    for (int n = 0; n < 4; n++) {
        int col = colbase + n * 16 + lr;
        bgv[n] = bg[col];
        ov[n] = oin[r * 256 + col];
    }

    floatx4 acc[4][4] = {};
#pragma unroll
    for (int kk = 0; kk < 256; kk += 32) {
        short8 a[4];
#pragma unroll
        for (int m = 0; m < 4; m++)
            a[m] = *reinterpret_cast<const short8*>(xa + (m * 16 + lr) * 264 + kk + lk4 * 8);
#pragma unroll
        for (int n = 0; n < 4; n++) {
            short8 b = *reinterpret_cast<const short8*>(wgT + (size_t)(colbase + n * 16 + lr) * 256 + kk + lk4 * 8);
#pragma unroll
            for (int m = 0; m < 4; m++)
                acc[m][n] = __builtin_amdgcn_mfma_f32_16x16x32_bf16(a[m], b, acc[m][n], 0, 0, 0);
        }
    }
    __syncthreads();

#pragma unroll
    for (int m = 0; m < 4; m++) {
#pragma unroll
        for (int n = 0; n < 4; n++) {
            int col = colbase + n * 16 + lr;
#pragma unroll
            for (int i = 0; i < 4; i++) {
                int row = m * 16 + lk4 * 4 + i;
                float z = acc[m][n][i] + bgv[n];
                float g = 1.f / (1.f + __expf(-z));
                xa[row * 264 + col] = f2bf(g * ov[n]);
            }
        }
    }
    __syncthreads();

    floatx4 acc2[4][4] = {};
#pragma unroll
    for (int kk = 0; kk < 256; kk += 32) {
        short8 ah[4];
#pragma unroll
        for (int m = 0; m < 4; m++)
            ah[m] = *reinterpret_cast<const short8*>(xa + (m * 16 + lr) * 264 + kk + lk4 * 8);
#pragma unroll
        for (int n = 0; n < 4; n++) {
            const size_t boff = (size_t)(colbase + n * 16 + lr) * 256 + kk + lk4 * 8;
            short8 bh = *reinterpret_cast<const short8*>(wfhi + boff);
            short8 bl = *reinterpret_cast<const short8*>(wflo + boff);
#pragma unroll
            for (int m = 0; m < 4; m++) {
                acc2[m][n] = __builtin_amdgcn_mfma_f32_16x16x32_bf16(ah[m], bh, acc2[m][n], 0, 0, 0);
                acc2[m][n] = __builtin_amdgcn_mfma_f32_16x16x32_bf16(ah[m], bl, acc2[m][n], 0, 0, 0);
            }
        }
    }

#pragma unroll
    for (int n = 0; n < 4; n++) {
        int col = colbase + n * 16 + lr;
        float bfc = bfv[col];
#pragma unroll
        for (int m = 0; m < 4; m++) {
#pragma unroll
            for (int i = 0; i < 4; i++) {
                int row = m * 16 + lk4 * 4 + i;
                out[((size_t)(s0 + row) * R_DIM + r) * C_DIM + col] = acc2[m][n][i] + bfc;
            }
        }
    }
}

// ---------------- K3 (xn-cache path): swapped MFMA + prefetch --------------
__global__ __launch_bounds__(256, 4) void k3c_kernel(
        const unsigned short* __restrict__ xnws, const unsigned short* __restrict__ wgT,
        const unsigned short* __restrict__ wfhi, const unsigned short* __restrict__ wflo,
        const float* __restrict__ oin, const float* __restrict__ bg,
        const float* __restrict__ bfv, float* __restrict__ out) {
    __shared__ unsigned short xa[64 * 256];   // xn then A2; chunk' = chunk ^ (row&7)
    const int sblk = blockIdx.x, r = blockIdx.y;
    const int s0 = sblk * BS;
    const int t = threadIdx.x;
    const int w = t >> 6, l = t & 63;

    // async stage: LDS linear, source pre-swizzled
    {
        const int c1 = l & 31;
        const int rh = l >> 5;
#pragma unroll
        for (int j = 0; j < 8; j++) {
            int row = w * 16 + 2 * j + rh;
            size_t src = ((size_t)(s0 + row) * R_DIM + r) * C_DIM + (size_t)((c1 ^ (row & 7)) * 8);
            async16(xa + (w * 16 + 2 * j) * 256, xnws + src);
        }
    }

    const int lr = l & 15, lk4 = l >> 4;
    const int colbase = w * 64;
    const int sw = lr & 7;
    const int c0base = colbase + lk4 * 4;   // + n*16 -> 4 contiguous cols

    float4 bg4[4], ov4[4], bf4[4];
#pragma unroll
    for (int n = 0; n < 4; n++) {
        bg4[n] = *reinterpret_cast<const float4*>(bg + c0base + n * 16);
        ov4[n] = *reinterpret_cast<const float4*>(oin + r * 256 + c0base + n * 16);
        bf4[n] = *reinterpret_cast<const float4*>(bfv + c0base + n * 16);
    }
    __syncthreads();

    // ---- pass 1: Z^T tile = mfma(Wg_frag, Xn_frag) ----
    floatx4 acc[4][4] = {};
    {
        const unsigned short* wgb = wgT + (size_t)(colbase + lr) * 256 + lk4 * 8;
        short8 cw[4], nw[4];
#pragma unroll
        for (int n = 0; n < 4; n++)
            cw[n] = *reinterpret_cast<const short8*>(wgb + n * 4096);
#pragma unroll
        for (int kk = 0; kk < 256; kk += 32) {
            if (kk < 224) {
#pragma unroll
                for (int n = 0; n < 4; n++)
                    nw[n] = *reinterpret_cast<const short8*>(wgb + n * 4096 + kk + 32);
            }
            short8 bx[4];
            const int ch = ((((kk >> 3) + lk4) ^ sw) * 8);
#pragma unroll
            for (int m = 0; m < 4; m++)
                bx[m] = *reinterpret_cast<const short8*>(xa + (m * 16 + lr) * 256 + ch);
#pragma unroll
            for (int n = 0; n < 4; n++)
#pragma unroll
                for (int m = 0; m < 4; m++)
                    acc[m][n] = __builtin_amdgcn_mfma_f32_16x16x32_bf16(cw[n], bx[m], acc[m][n], 0, 0, 0);
            if (kk < 224) {
#pragma unroll
                for (int n = 0; n < 4; n++) cw[n] = nw[n];
            }
        }
    }
    __syncthreads();   // all xn reads done

    // ---- gate: A2[row, 4 contiguous cols] -> 8B swizzled LDS writes ----
#pragma unroll
    for (int m = 0; m < 4; m++) {
        const int row = m * 16 + lr;
        unsigned short* rowp = xa + row * 256;
#pragma unroll
        for (int n = 0; n < 4; n++) {
            const int c0 = c0base + n * 16;
            ushort4v pk;
#pragma unroll
            for (int j = 0; j < 4; j++) {
                float z = acc[m][n][j] + ((const float*)&bg4[n])[j];
                float g = 1.f / (1.f + __expf(-z));
                pk[j] = f2bf(g * ((const float*)&ov4[n])[j]);
            }
            const int dst = (((c0 >> 3) ^ sw) * 8) + (c0 & 7);
            *reinterpret_cast<ushort4v*>(rowp + dst) = pk;
        }
    }
    __syncthreads();

    // ---- pass 2: out^T tile = mfma(Wf_frag, A2_frag), bf16x2 on Wf ----
    floatx4 acc2[4][4] = {};
    {
        const unsigned short* whb = wfhi + (size_t)(colbase + lr) * 256 + lk4 * 8;
        const unsigned short* wlb = wflo + (size_t)(colbase + lr) * 256 + lk4 * 8;
        short8 chw[4], clw[4], nhw[4], nlw[4];
#pragma unroll
        for (int n = 0; n < 4; n++) {
            chw[n] = *reinterpret_cast<const short8*>(whb + n * 4096);
            clw[n] = *reinterpret_cast<const short8*>(wlb + n * 4096);
        }
#pragma unroll
        for (int kk = 0; kk < 256; kk += 32) {
            if (kk < 224) {
#pragma unroll
                for (int n = 0; n < 4; n++) {
                    nhw[n] = *reinterpret_cast<const short8*>(whb + n * 4096 + kk + 32);
                    nlw[n] = *reinterpret_cast<const short8*>(wlb + n * 4096 + kk + 32);
                }
            }
            short8 ba[4];
            const int ch = ((((kk >> 3) + lk4) ^ sw) * 8);
#pragma unroll
            for (int m = 0; m < 4; m++)
                ba[m] = *reinterpret_cast<const short8*>(xa + (m * 16 + lr) * 256 + ch);
#pragma unroll
            for (int n = 0; n < 4; n++)
#pragma unroll
                for (int m = 0; m < 4; m++) {
                    acc2[m][n] = __builtin_amdgcn_mfma_f32_16x16x32_bf16(chw[n], ba[m], acc2[m][n], 0, 0, 0);
                    acc2[m][n] = __builtin_amdgcn_mfma_f32_16x16x32_bf16(clw[n], ba[m], acc2[m][n], 0, 0, 0);
                }
            if (kk < 224) {
#pragma unroll
                for (int n = 0; n < 4; n++) { chw[n] = nhw[n]; clw[n] = nlw[n]; }
            }
        }
    }

    // ---- epilogue: float4 stores ----
#pragma unroll
    for (int m = 0; m < 4; m++) {
        const int row = m * 16 + lr;
        float* orow = out + ((size_t)(s0 + row) * R_DIM + r) * C_DIM;
#pragma unroll
        for (int n = 0; n < 4; n++) {
            float4 o4;
            o4.x = acc2[m][n][0] + ((const float*)&bf4[n])[0];
            o4.y = acc2[m][n][1] + ((const float*)&bf4[n])[1];
            o4.z = acc2[m][n][2] + ((const float*)&bf4[n])[2];
            o4.w = acc2[m][n][3] + ((const float*)&bf4[n])[3];
            *reinterpret_cast<float4*>(orow + c0base + n * 16) = o4;
        }
    }
}

extern "C" void kernel_launch(void* const* d_in, const int* in_sizes, int n_in,
                              void* d_out, int out_size, void* d_ws, size_t ws_size,
                              hipStream_t stream) {
    const float* x1   = (const float*)d_in[0];
    const float* mask = (const float*)d_in[1];
    const float* lns  = (const float*)d_in[2];
    const float* lnb  = (const float*)d_in[3];
    const float* Wq   = (const float*)d_in[4];
    const float* Wk   = (const float*)d_in[5];
    const float* Wv   = (const float*)d_in[6];
    const float* Wg   = (const float*)d_in[7];
    const float* bg   = (const float*)d_in[8];
    const float* Wf   = (const float*)d_in[9];
    const float* bfv  = (const float*)d_in[10];

    char* ws = (char*)d_ws;
    unsigned short* wgT  = (unsigned short*)(ws);                 // 128 KB
    unsigned short* wfhi = (unsigned short*)(ws + 131072);        // 128 KB
    unsigned short* wflo = (unsigned short*)(ws + 262144);        // 128 KB
    unsigned short* wkvT = (unsigned short*)(ws + 393216);        // 32 KB
    float* qsum = (float*)(ws + 425984);                          // 8 MB
    float* msum = (float*)(ws + 425984 + 8388608);                // 32 KB
    float* oo   = (float*)(ws + 425984 + 8388608 + 32768);        // 512 KB
    unsigned short* xnws = (unsigned short*)(ws + XN_OFF);        // 256 MB (if present)
    unsigned short* kv = (unsigned short*)d_out;
    float* out = (float*)d_out;

    const bool big_ws = ws_size >= (size_t)XN_OFF + (size_t)XN_BYTES;

    prep_kernel<<<256, 256, 0, stream>>>(Wk, Wv, Wg, Wf, wgT, wfhi, wflo, wkvT);
    if (big_ws) {
        k1_kernel<1><<<dim3(SB, R_DIM), 256, 0, stream>>>(x1, mask, lns, lnb, wkvT, kv, qsum, msum, xnws);
        k2_kernel<<<R_DIM, 256, 0, stream>>>(mask, Wq, qsum, msum, kv, oo);
        k3c_kernel<<<dim3(SB, R_DIM), 256, 0, stream>>>(xnws, wgT, wfhi, wflo, oo, bg, bfv, out);
    } else {
        k1_kernel<0><<<dim3(SB, R_DIM), 256, 0, stream>>>(x1, mask, lns, lnb, wkvT, kv, qsum, msum, nullptr);
        k2_kernel<<<R_DIM, 256, 0, stream>>>(mask, Wq, qsum, msum, kv, oo);
        k3r_kernel<<<dim3(SB, R_DIM), 256, 0, stream>>>(x1, lns, lnb, wgT, wfhi, wflo, oo, bg, bfv, out);
    }
}